// Round 6
// baseline (24.998 us; speedup 1.0000x reference)
//
#include <hip/hip_runtime.h>

#define NC  4
#define TPB 256          // threads per block
#define WPT 2            // walkers per thread
#define WPB (TPB * WPT)  // 512 walkers per block

__global__ __launch_bounds__(TPB) void wvfn_kernel(
    const float* __restrict__ Rs,   // [W, 4, 3] f32
    const float* __restrict__ A,    // [4] f32
    const float* __restrict__ C,    // [4] f32 (complex64 -> real f32 by harness)
    float* __restrict__ out,        // [W f32 (out0)] ++ [W f32 (out1)]
    int W)
{
    __shared__ float4 sh[WPB * 3];  // 512 walkers * 48B = 24 KB

    const int t = threadIdx.x;
    const size_t blk_first_q = (size_t)blockIdx.x * (WPB * 3);
    const size_t total_q     = (size_t)W * 3;

    // ---- coalesced global -> LDS: 6 contiguous 1024B wave transactions in flight ----
    const float4* g = (const float4*)Rs;
    #pragma unroll
    for (int k = 0; k < 3 * WPT; ++k) {
        size_t q = blk_first_q + t + (size_t)k * TPB;
        if (q < total_q) sh[t + k * TPB] = g[q];
    }

    // ---- hoist uniform ansatz coefficients (scalar loads, overlap with LDS fill) ----
    float invA[NC], lap1[NC], lap2[NC], cre[NC];
    #pragma unroll
    for (int n = 0; n < NC; ++n) {
        float ia = 1.0f / A[n];
        invA[n] = ia;
        lap1[n] = (float)NC * ia * ia;
        lap2[n] = 2.0f * ia;
        cre[n]  = C[n];
    }

    __syncthreads();

    #pragma unroll
    for (int u = 0; u < WPT; ++u) {
        const int li = t + u * TPB;               // local walker in block
        const int w  = blockIdx.x * WPB + li;     // global walker
        if (w >= W) break;

        // LDS read at byte 48*li: ds_read_b128, every bank hit exactly 8x/wave (min) -> conflict-free
        float4 q0 = sh[3 * li + 0];
        float4 q1 = sh[3 * li + 1];
        float4 q2 = sh[3 * li + 2];

        float x0 = q0.x, y0 = q0.y, z0 = q0.z;
        float x1 = q0.w, y1 = q1.x, z1 = q1.y;
        float x2 = q1.z, y2 = q1.w, z2 = q2.x;
        float x3 = q2.y, y3 = q2.z, z3 = q2.w;

        float d0 = x0*x0 + y0*y0 + z0*z0;
        float d1 = x1*x1 + y1*y1 + z1*z1;
        float d2 = x2*x2 + y2*y2 + z2*z2;
        float d3 = x3*x3 + y3*y3 + z3*z3;

        float i0 = rsqrtf(d0), i1 = rsqrtf(d1), i2 = rsqrtf(d2), i3 = rsqrtf(d3);
        float r_sum    = d0*i0 + d1*i1 + d2*i2 + d3*i3;
        float invr_sum = i0 + i1 + i2 + i3;

        // all-pairs Coulomb (VB = 1)
        float V;
        {
            float dx, dy, dz, dd, s = 0.0f;
            dx = x0-x1; dy = y0-y1; dz = z0-z1; dd = dx*dx+dy*dy+dz*dz; s += rsqrtf(dd);
            dx = x0-x2; dy = y0-y2; dz = z0-z2; dd = dx*dx+dy*dy+dz*dz; s += rsqrtf(dd);
            dx = x0-x3; dy = y0-y3; dz = z0-z3; dd = dx*dx+dy*dy+dz*dz; s += rsqrtf(dd);
            dx = x1-x2; dy = y1-y2; dz = z1-z2; dd = dx*dx+dy*dy+dz*dz; s += rsqrtf(dd);
            dx = x1-x3; dy = y1-y3; dz = z1-z3; dd = dx*dx+dy*dy+dz*dz; s += rsqrtf(dd);
            dx = x2-x3; dy = y2-y3; dz = z2-z3; dd = dx*dx+dy*dy+dz*dz; s += rsqrtf(dd);
            V = -s;
        }

        // psi, nabla_psi (C real)
        float psi = 0.0f, nab = 0.0f;
        #pragma unroll
        for (int n = 0; n < NC; ++n) {
            float e   = expf(-r_sum * invA[n]);
            float lap = lap1[n] - lap2[n] * invr_sum;
            psi += cre[n] * e;
            nab += cre[n] * e * lap;
        }

        float H = -0.5f * nab + V * psi;

        __builtin_nontemporal_store(psi * H,   &out[w]);
        __builtin_nontemporal_store(psi * psi, &out[(size_t)W + w]);
    }
}

extern "C" void kernel_launch(void* const* d_in, const int* in_sizes, int n_in,
                              void* d_out, int out_size, void* d_ws, size_t ws_size,
                              hipStream_t stream) {
    const float* Rs = (const float*)d_in[0];
    const float* A  = (const float*)d_in[1];
    const float* C  = (const float*)d_in[2];
    float* out = (float*)d_out;

    int W = in_sizes[0] / 12;                  // [W, 4, 3]
    int grid = (W + WPB - 1) / WPB;
    wvfn_kernel<<<grid, TPB, 0, stream>>>(Rs, A, C, out, W);
}